// Round 4
// baseline (136.925 us; speedup 1.0000x reference)
//
#include <hip/hip_runtime.h>

typedef __bf16 bf16;
typedef __bf16 bf16x4 __attribute__((ext_vector_type(4)));
typedef __bf16 bf16x8 __attribute__((ext_vector_type(8)));
typedef float f32x4 __attribute__((ext_vector_type(4)));

#define SEQ 1024
#define EMB 1024
#define NH 16
#define HD 64
#define M2 2047   // 2*MAX_POS - 1

// ---------------------------------------------------------------------------
// Kernel 1 (R2 version, unchanged): P[2048][1024] (bf16) = gather(posEmb) @ W
// ---------------------------------------------------------------------------
__global__ __launch_bounds__(256) void gemm1_kernel(const float* __restrict__ posEmb,
                                                    const float* __restrict__ W,
                                                    bf16* __restrict__ P) {
  __shared__ bf16 As[64][72];
  __shared__ bf16 Bs[64][72];
  const int tid  = threadIdx.x;
  const int lane = tid & 63;
  const int wave = tid >> 6;
  const int wr = wave >> 1, wc = wave & 1;
  const int m0 = blockIdx.y * 64;
  const int n0 = blockIdx.x * 64;

  f32x4 acc[2][2] = {};

  for (int k0 = 0; k0 < EMB; k0 += 64) {
    {
      const int row = tid >> 2;
      const int c0  = (tid & 3) * 16;
      int g = m0 + row;
      if (g > M2 - 1) g = M2 - 1;
      const float4* src = reinterpret_cast<const float4*>(posEmb + (size_t)g * EMB + k0 + c0);
      #pragma unroll
      for (int i = 0; i < 4; ++i) {
        float4 v = src[i];
        bf16x4 bb = { (bf16)v.x, (bf16)v.y, (bf16)v.z, (bf16)v.w };
        *reinterpret_cast<bf16x4*>(&As[row][c0 + 4 * i]) = bb;
      }
    }
    {
      const int n  = tid & 63;
      const int kg = tid >> 6;
      #pragma unroll
      for (int u = 0; u < 4; ++u) {
        bf16x4 bb;
        #pragma unroll
        for (int e = 0; e < 4; ++e) {
          int k = kg * 16 + u * 4 + e;
          bb[e] = (bf16)W[(size_t)(k0 + k) * EMB + n0 + n];
        }
        *reinterpret_cast<bf16x4*>(&Bs[n][kg * 16 + u * 4]) = bb;
      }
    }
    __syncthreads();
    #pragma unroll
    for (int ks = 0; ks < 2; ++ks) {
      bf16x8 a[2], b[2];
      #pragma unroll
      for (int x = 0; x < 2; ++x) {
        a[x] = *reinterpret_cast<const bf16x8*>(&As[wr * 32 + x * 16 + (lane & 15)][ks * 32 + 8 * (lane >> 4)]);
        b[x] = *reinterpret_cast<const bf16x8*>(&Bs[wc * 32 + x * 16 + (lane & 15)][ks * 32 + 8 * (lane >> 4)]);
      }
      #pragma unroll
      for (int x = 0; x < 2; ++x)
        #pragma unroll
        for (int y = 0; y < 2; ++y)
          acc[x][y] = __builtin_amdgcn_mfma_f32_16x16x32_bf16(a[x], b[y], acc[x][y], 0, 0, 0);
    }
    __syncthreads();
  }

  #pragma unroll
  for (int x = 0; x < 2; ++x)
    #pragma unroll
    for (int y = 0; y < 2; ++y)
      #pragma unroll
      for (int r = 0; r < 4; ++r) {
        int row = m0 + wr * 32 + x * 16 + (lane >> 4) * 4 + r;
        int col = n0 + wc * 32 + y * 16 + (lane & 15);
        P[(size_t)row * EMB + col] = (bf16)acc[x][y][r];
      }
}

// ---------------------------------------------------------------------------
// Kernel 2 (R2 version, unchanged): band GEMM with m-loop inside the block.
// ---------------------------------------------------------------------------
__global__ __launch_bounds__(256) void band2_kernel(const float* __restrict__ q,
                                                    const bf16* __restrict__ P,
                                                    float* __restrict__ out) {
  __shared__ bf16 Pbuf[2][64 * 64];
  const int tid  = threadIdx.x;
  const int lane = tid & 63;
  const int wave = tid >> 6;
  const int wr = wave >> 1, wc = wave & 1;

  const int i0 = blockIdx.x * 64;
  const int hb = blockIdx.y;
  const int h  = hb >> 1;
  const int b  = hb & 1;

  bf16x8 a[2][2];
  {
    const float* qbase = q + ((size_t)(h * (2 * SEQ) + b * SEQ)) * HD;
    const int row = i0 + wr * 32 + (lane & 15);
    const int kof = 8 * (lane >> 4);
    #pragma unroll
    for (int x = 0; x < 2; ++x)
      #pragma unroll
      for (int ks = 0; ks < 2; ++ks) {
        const float* src = qbase + (size_t)(row + x * 16) * HD + ks * 32 + kof;
        float4 v0 = *reinterpret_cast<const float4*>(src);
        float4 v1 = *reinterpret_cast<const float4*>(src + 4);
        bf16x8 f = { (bf16)v0.x, (bf16)v0.y, (bf16)v0.z, (bf16)v0.w,
                     (bf16)v1.x, (bf16)v1.y, (bf16)v1.z, (bf16)v1.w };
        a[x][ks] = f;
      }
  }

  const int m_base = (SEQ - 1) - (i0 + 63);
  const int tb = blockIdx.z * 9;
  const int te = (blockIdx.z == 0) ? 9 : 17;

  auto STAGE = [&](int bi, int t) {
    const int m0 = m_base + t * 64;
    const char* Pb = reinterpret_cast<const char*>(P);
    #pragma unroll
    for (int i = 0; i < 2; ++i) {
      int s   = wave * 128 + i * 64 + lane;
      int row = s >> 3;
      int cs  = s & 7;
      int cd  = cs ^ (row & 7);
      const void* g = Pb + ((size_t)(m0 + row) * EMB + h * HD) * 2 + cd * 16;
      char* l = reinterpret_cast<char*>(&Pbuf[bi][0]) + (wave * 128 + i * 64) * 16;
      __builtin_amdgcn_global_load_lds(
          (const __attribute__((address_space(1))) void*)g,
          (__attribute__((address_space(3))) void*)l, 16, 0, 0);
    }
  };

  const size_t outbase = (size_t)hb << 20;

  STAGE(0, tb);
  __syncthreads();

  int cur = 0;
  for (int t = tb; t < te; ++t) {
    if (t + 1 < te) STAGE(cur ^ 1, t + 1);

    const char* buf = reinterpret_cast<const char*>(&Pbuf[cur][0]);
    f32x4 acc[2][2] = {};
    #pragma unroll
    for (int ks = 0; ks < 2; ++ks) {
      bf16x8 bb[2];
      #pragma unroll
      for (int y = 0; y < 2; ++y) {
        int mrow  = wc * 32 + y * 16 + (lane & 15);
        int chunk = ks * 4 + (lane >> 4);
        int sw    = chunk ^ (mrow & 7);
        bb[y] = *reinterpret_cast<const bf16x8*>(buf + mrow * 128 + sw * 16);
      }
      #pragma unroll
      for (int x = 0; x < 2; ++x)
        #pragma unroll
        for (int y = 0; y < 2; ++y)
          acc[x][y] = __builtin_amdgcn_mfma_f32_16x16x32_bf16(a[x][ks], bb[y], acc[x][y], 0, 0, 0);
    }

    const int m0 = m_base + t * 64;
    #pragma unroll
    for (int x = 0; x < 2; ++x)
      #pragma unroll
      for (int y = 0; y < 2; ++y)
        #pragma unroll
        for (int r = 0; r < 4; ++r) {
          int i = i0 + wr * 32 + x * 16 + (lane >> 4) * 4 + r;
          int m = m0 + wc * 32 + y * 16 + (lane & 15);
          int j = m - (SEQ - 1) + i;
          if ((unsigned)j < SEQ)
            out[outbase + (size_t)i * SEQ + j] = acc[x][y][r];
        }

    __syncthreads();
    cur ^= 1;
  }
}

extern "C" void kernel_launch(void* const* d_in, const int* in_sizes, int n_in,
                              void* d_out, int out_size, void* d_ws, size_t ws_size,
                              hipStream_t stream) {
  const float* query  = (const float*)d_in[0];   // [2,16,1024,64]
  const float* posEmb = (const float*)d_in[1];   // [2047,1024]
  const float* W      = (const float*)d_in[2];   // [1024,1024]
  float* out = (float*)d_out;                    // [2,16,1024,1024]
  bf16* P = (bf16*)d_ws;                         // [2048][1024] bf16 = 4 MB

  gemm1_kernel<<<dim3(16, 32), 256, 0, stream>>>(posEmb, W, P);
  // ATTRIBUTION: band2 launched 3x (idempotent — identical writes each pass).
  // band2 marginal cost = (T - 61.3 - 2*gap) / 2.
  band2_kernel<<<dim3(16, 32, 2), 256, 0, stream>>>(query, P, out);
  band2_kernel<<<dim3(16, 32, 2), 256, 0, stream>>>(query, P, out);
  band2_kernel<<<dim3(16, 32, 2), 256, 0, stream>>>(query, P, out);
}

// Round 5
// 63.314 us; speedup vs baseline: 2.1626x; 2.1626x over previous
//
#include <hip/hip_runtime.h>

typedef __bf16 bf16;
typedef __bf16 bf16x4 __attribute__((ext_vector_type(4)));
typedef __bf16 bf16x8 __attribute__((ext_vector_type(8)));
typedef float f32x4 __attribute__((ext_vector_type(4)));

#define SEQ 1024
#define EMB 1024
#define NH 16
#define HD 64
#define M2 2047   // 2*MAX_POS - 1

// ---------------------------------------------------------------------------
// Kernel 1 (R2 version, unchanged): P[2048][1024] (bf16) = gather(posEmb) @ W
// ---------------------------------------------------------------------------
__global__ __launch_bounds__(256) void gemm1_kernel(const float* __restrict__ posEmb,
                                                    const float* __restrict__ W,
                                                    bf16* __restrict__ P) {
  __shared__ bf16 As[64][72];
  __shared__ bf16 Bs[64][72];
  const int tid  = threadIdx.x;
  const int lane = tid & 63;
  const int wave = tid >> 6;
  const int wr = wave >> 1, wc = wave & 1;
  const int m0 = blockIdx.y * 64;
  const int n0 = blockIdx.x * 64;

  f32x4 acc[2][2] = {};

  for (int k0 = 0; k0 < EMB; k0 += 64) {
    {
      const int row = tid >> 2;
      const int c0  = (tid & 3) * 16;
      int g = m0 + row;
      if (g > M2 - 1) g = M2 - 1;
      const float4* src = reinterpret_cast<const float4*>(posEmb + (size_t)g * EMB + k0 + c0);
      #pragma unroll
      for (int i = 0; i < 4; ++i) {
        float4 v = src[i];
        bf16x4 bb = { (bf16)v.x, (bf16)v.y, (bf16)v.z, (bf16)v.w };
        *reinterpret_cast<bf16x4*>(&As[row][c0 + 4 * i]) = bb;
      }
    }
    {
      const int n  = tid & 63;
      const int kg = tid >> 6;
      #pragma unroll
      for (int u = 0; u < 4; ++u) {
        bf16x4 bb;
        #pragma unroll
        for (int e = 0; e < 4; ++e) {
          int k = kg * 16 + u * 4 + e;
          bb[e] = (bf16)W[(size_t)(k0 + k) * EMB + n0 + n];
        }
        *reinterpret_cast<bf16x4*>(&Bs[n][kg * 16 + u * 4]) = bb;
      }
    }
    __syncthreads();
    #pragma unroll
    for (int ks = 0; ks < 2; ++ks) {
      bf16x8 a[2], b[2];
      #pragma unroll
      for (int x = 0; x < 2; ++x) {
        a[x] = *reinterpret_cast<const bf16x8*>(&As[wr * 32 + x * 16 + (lane & 15)][ks * 32 + 8 * (lane >> 4)]);
        b[x] = *reinterpret_cast<const bf16x8*>(&Bs[wc * 32 + x * 16 + (lane & 15)][ks * 32 + 8 * (lane >> 4)]);
      }
      #pragma unroll
      for (int x = 0; x < 2; ++x)
        #pragma unroll
        for (int y = 0; y < 2; ++y)
          acc[x][y] = __builtin_amdgcn_mfma_f32_16x16x32_bf16(a[x], b[y], acc[x][y], 0, 0, 0);
    }
    __syncthreads();
  }

  #pragma unroll
  for (int x = 0; x < 2; ++x)
    #pragma unroll
    for (int y = 0; y < 2; ++y)
      #pragma unroll
      for (int r = 0; r < 4; ++r) {
        int row = m0 + wr * 32 + x * 16 + (lane >> 4) * 4 + r;
        int col = n0 + wc * 32 + y * 16 + (lane & 15);
        P[(size_t)row * EMB + col] = (bf16)acc[x][y][r];
      }
}

// ---------------------------------------------------------------------------
// Kernel 2: band GEMM, m-loop in-block. CHANGED vs R2: per-tile sync is now
//   counted `s_waitcnt vmcnt(16)` + raw s_barrier (T4) instead of
//   __syncthreads()'s full vmcnt(0) store-drain. Loads are issued FIRST each
//   iteration, stores after, so vmcnt(16) drains the 2 prefetch loads plus
//   the PREVIOUS tile's stores while leaving this tile's 16 stores in flight.
// ---------------------------------------------------------------------------
__global__ __launch_bounds__(256) void band2_kernel(const float* __restrict__ q,
                                                    const bf16* __restrict__ P,
                                                    float* __restrict__ out) {
  __shared__ bf16 Pbuf[2][64 * 64];
  const int tid  = threadIdx.x;
  const int lane = tid & 63;
  const int wave = tid >> 6;
  const int wr = wave >> 1, wc = wave & 1;

  const int i0 = blockIdx.x * 64;
  const int hb = blockIdx.y;
  const int h  = hb >> 1;
  const int b  = hb & 1;

  bf16x8 a[2][2];
  {
    const float* qbase = q + ((size_t)(h * (2 * SEQ) + b * SEQ)) * HD;
    const int row = i0 + wr * 32 + (lane & 15);
    const int kof = 8 * (lane >> 4);
    #pragma unroll
    for (int x = 0; x < 2; ++x)
      #pragma unroll
      for (int ks = 0; ks < 2; ++ks) {
        const float* src = qbase + (size_t)(row + x * 16) * HD + ks * 32 + kof;
        float4 v0 = *reinterpret_cast<const float4*>(src);
        float4 v1 = *reinterpret_cast<const float4*>(src + 4);
        bf16x8 f = { (bf16)v0.x, (bf16)v0.y, (bf16)v0.z, (bf16)v0.w,
                     (bf16)v1.x, (bf16)v1.y, (bf16)v1.z, (bf16)v1.w };
        a[x][ks] = f;
      }
  }

  const int m_base = (SEQ - 1) - (i0 + 63);
  const int tb = blockIdx.z * 9;
  const int te = (blockIdx.z == 0) ? 9 : 17;

  auto STAGE = [&](int bi, int t) {
    const int m0 = m_base + t * 64;
    const char* Pb = reinterpret_cast<const char*>(P);
    #pragma unroll
    for (int i = 0; i < 2; ++i) {
      int s   = wave * 128 + i * 64 + lane;
      int row = s >> 3;
      int cs  = s & 7;
      int cd  = cs ^ (row & 7);
      const void* g = Pb + ((size_t)(m0 + row) * EMB + h * HD) * 2 + cd * 16;
      char* l = reinterpret_cast<char*>(&Pbuf[bi][0]) + (wave * 128 + i * 64) * 16;
      __builtin_amdgcn_global_load_lds(
          (const __attribute__((address_space(1))) void*)g,
          (__attribute__((address_space(3))) void*)l, 16, 0, 0);
    }
  };

  const size_t outbase = (size_t)hb << 20;

  STAGE(0, tb);
  asm volatile("s_waitcnt vmcnt(0)" ::: "memory");
  __builtin_amdgcn_s_barrier();

  int cur = 0;
  for (int t = tb; t < te; ++t) {
    if (t + 1 < te) STAGE(cur ^ 1, t + 1);   // loads first (oldest vmem this iter)

    const char* buf = reinterpret_cast<const char*>(&Pbuf[cur][0]);
    f32x4 acc[2][2] = {};
    #pragma unroll
    for (int ks = 0; ks < 2; ++ks) {
      bf16x8 bb[2];
      #pragma unroll
      for (int y = 0; y < 2; ++y) {
        int mrow  = wc * 32 + y * 16 + (lane & 15);
        int chunk = ks * 4 + (lane >> 4);
        int sw    = chunk ^ (mrow & 7);
        bb[y] = *reinterpret_cast<const bf16x8*>(buf + mrow * 128 + sw * 16);
      }
      #pragma unroll
      for (int x = 0; x < 2; ++x)
        #pragma unroll
        for (int y = 0; y < 2; ++y)
          acc[x][y] = __builtin_amdgcn_mfma_f32_16x16x32_bf16(a[x][ks], bb[y], acc[x][y], 0, 0, 0);
    }

    const int m0 = m_base + t * 64;
    #pragma unroll
    for (int x = 0; x < 2; ++x)
      #pragma unroll
      for (int y = 0; y < 2; ++y)
        #pragma unroll
        for (int r = 0; r < 4; ++r) {
          int i = i0 + wr * 32 + x * 16 + (lane >> 4) * 4 + r;
          int m = m0 + wc * 32 + y * 16 + (lane & 15);
          int j = m - (SEQ - 1) + i;
          if ((unsigned)j < SEQ)
            out[outbase + (size_t)i * SEQ + j] = acc[x][y][r];
        }

    // T4 counted sync: drain prefetch loads + previous tile's stores only;
    // leave this tile's 16 stores in flight across the barrier.
    __builtin_amdgcn_sched_barrier(0);
    asm volatile("s_waitcnt vmcnt(16)" ::: "memory");
    __builtin_amdgcn_sched_barrier(0);
    __builtin_amdgcn_s_barrier();
    cur ^= 1;
  }
}

extern "C" void kernel_launch(void* const* d_in, const int* in_sizes, int n_in,
                              void* d_out, int out_size, void* d_ws, size_t ws_size,
                              hipStream_t stream) {
  const float* query  = (const float*)d_in[0];   // [2,16,1024,64]
  const float* posEmb = (const float*)d_in[1];   // [2047,1024]
  const float* W      = (const float*)d_in[2];   // [1024,1024]
  float* out = (float*)d_out;                    // [2,16,1024,1024]
  bf16* P = (bf16*)d_ws;                         // [2048][1024] bf16 = 4 MB

  gemm1_kernel<<<dim3(16, 32), 256, 0, stream>>>(posEmb, W, P);
  band2_kernel<<<dim3(16, 32, 2), 256, 0, stream>>>(query, P, out);
}